// Round 1
// baseline (34110.803 us; speedup 1.0000x reference)
//
#include <hip/hip_runtime.h>

#define MSZ (1024*1024)

// ===================== small vector kernels =====================

__global__ __launch_bounds__(1024) void prep_k(const float* __restrict__ inp, const float* __restrict__ iw,
    const float* __restrict__ ib, const float* __restrict__ aw, const float* __restrict__ ab,
    float* __restrict__ xv, float* __restrict__ atte) {
  __shared__ float red[1024];
  int t = threadIdx.x;
  float x = inp[t] * iw[t] + ib[t];
  float s = x * (aw[t] + ab[0]);
  xv[t] = x;
  red[t] = s;
  __syncthreads();
  for (int o = 512; o > 0; o >>= 1) { if (t < o) red[t] = fmaxf(red[t], red[t + o]); __syncthreads(); }
  atte[t] = expf(s - red[0]);
}

__global__ void setdiag_k(float* __restrict__ P, const float* __restrict__ atte) {
  int idx = blockIdx.x * 256 + threadIdx.x;
  int r = idx >> 10, c = idx & 1023;
  P[idx] = (r == c) ? atte[r] : 0.0f;
}

__global__ void diagadd_k(float* __restrict__ M, const float* __restrict__ atte) {
  int i = blockIdx.x * 256 + threadIdx.x;
  M[(size_t)i * 1024 + i] += atte[i];
}

__global__ __launch_bounds__(256) void sens_k(const float* __restrict__ sw, const float* __restrict__ ssig,
    const float* __restrict__ smu, const float* __restrict__ serev, const float* __restrict__ smask,
    const float* __restrict__ xv, float* __restrict__ wns, float* __restrict__ wds) {
  __shared__ float rn[256], rd[256];
  int i = blockIdx.x, t = threadIdx.x;
  float xi = xv[i];
  float n = 0.f, d = 0.f;
  for (int j = t; j < 1024; j += 256) {
    int idx = i * 1024 + j;
    float z = ssig[idx] * (xi - smu[idx]);
    float sg = 1.0f / (1.0f + expf(-z));
    float act = sw[idx] * sg * smask[idx];
    n += act * serev[idx];
    d += act;
  }
  rn[t] = n; rd[t] = d;
  __syncthreads();
  for (int o = 128; o > 0; o >>= 1) { if (t < o) { rn[t] += rn[t + o]; rd[t] += rd[t + o]; } __syncthreads(); }
  if (t == 0) { wns[i] = rn[0]; wds[i] = rd[0]; }
}

__global__ __launch_bounds__(256) void gcn_k(const float* __restrict__ adj, const float* __restrict__ hin,
    float* __restrict__ hout, const float* __restrict__ gcw, const float* __restrict__ gcb) {
  __shared__ float red[256];
  int i = blockIdx.x, t = threadIdx.x;
  float s = 0.f;
  for (int j = t; j < 1024; j += 256) s += adj[(size_t)i * 1024 + j] * hin[j];
  red[t] = s; __syncthreads();
  for (int o = 128; o > 0; o >>= 1) { if (t < o) red[t] += red[t + o]; __syncthreads(); }
  if (t == 0) hout[i] = fmaxf(gcw[0] * red[0] + gcb[0], 0.0f);
}

__global__ __launch_bounds__(256) void matvec_n_k(const float* __restrict__ M, const float* __restrict__ v,
    float* __restrict__ out) {
  __shared__ float red[256];
  int i = blockIdx.x, t = threadIdx.x;
  float s = 0.f;
  for (int j = t; j < 1024; j += 256) s += M[(size_t)i * 1024 + j] * v[j];
  red[t] = s; __syncthreads();
  for (int o = 128; o > 0; o >>= 1) { if (t < o) red[t] += red[t + o]; __syncthreads(); }
  if (t == 0) out[i] = red[0];
}

__global__ __launch_bounds__(256) void matvec_t_k(const float* __restrict__ M, const float* __restrict__ v,
    float* __restrict__ out) {
  int j = blockIdx.x * 256 + threadIdx.x;
  float s = 0.f;
  for (int i = 0; i < 1024; i++) s += M[(size_t)i * 1024 + j] * v[i];
  out[j] = s;
}

__global__ void gctrl_k(const float* __restrict__ control, const float* __restrict__ u, float* __restrict__ g) {
  int t = blockIdx.x * 256 + threadIdx.x;
  g[t] = control[t] - u[t] * (1.0f / 1024.0f);
}

__global__ void copylap_k(const float4* __restrict__ src, float4* __restrict__ dst) {
  int i = blockIdx.x * 256 + threadIdx.x;
  dst[i] = src[i];
}

// ===================== fp32 tiled GEMM (VALU; no fp32 MFMA on CDNA4) =====================
// C[M,N] (MODE 0: =, MODE 1: -=) sum_k op(A)[m][k] * op(B)[k][n]
template<int TA, int TB, int MODE>
__global__ __launch_bounds__(256) void gemm_k(const float* __restrict__ A, const float* __restrict__ B,
    float* __restrict__ C, int M, int N, int K, int lda, int ldb, int ldc, int triSkip) {
  if (triSkip && (int)blockIdx.x > (int)blockIdx.y) return;  // lower-triangle-only update
  __shared__ float As[16][132];
  __shared__ float Bs[16][132];
  int row0 = blockIdx.y * 128, col0 = blockIdx.x * 128;
  int t = threadIdx.x;
  int tx = t & 15, ty = t >> 4;
  float acc[8][8] = {};
  for (int k0 = 0; k0 < K; k0 += 16) {
    #pragma unroll
    for (int r = 0; r < 8; r++) {
      int e = r * 256 + t;
      int am, ak;
      if (TA == 0) { am = e >> 4; ak = e & 15; }
      else         { ak = e >> 7; am = e & 127; }
      int gm = row0 + am, gk = k0 + ak;
      float av = 0.f;
      if (gm < M && gk < K) av = TA ? A[(size_t)gk * lda + gm] : A[(size_t)gm * lda + gk];
      As[ak][am] = av;
      int bk, bn;
      if (TB == 0) { bk = e >> 7; bn = e & 127; }
      else         { bn = e >> 4; bk = e & 15; }
      int gn = col0 + bn, gk2 = k0 + bk;
      float bv = 0.f;
      if (gn < N && gk2 < K) bv = TB ? B[(size_t)gn * ldb + gk2] : B[(size_t)gk2 * ldb + gn];
      Bs[bk][bn] = bv;
    }
    __syncthreads();
    #pragma unroll
    for (int k = 0; k < 16; k++) {
      float a[8], b[8];
      #pragma unroll
      for (int i = 0; i < 8; i++) a[i] = As[k][ty * 8 + i];
      #pragma unroll
      for (int j = 0; j < 8; j++) b[j] = Bs[k][tx * 8 + j];
      #pragma unroll
      for (int i = 0; i < 8; i++)
        #pragma unroll
        for (int j = 0; j < 8; j++)
          acc[i][j] += a[i] * b[j];
    }
    __syncthreads();
  }
  #pragma unroll
  for (int i = 0; i < 8; i++) {
    int gm = row0 + ty * 8 + i;
    if (gm >= M) continue;
    #pragma unroll
    for (int j = 0; j < 8; j++) {
      int gn = col0 + tx * 8 + j;
      if (gn >= N) continue;
      size_t o = (size_t)gm * ldc + gn;
      if (MODE == 0) C[o] = acc[i][j];
      else C[o] -= acc[i][j];
    }
  }
}

// ===================== Cholesky building blocks (block size 64) =====================

// Factor 64x64 diagonal block in-register (one wave; lane l = row l; fully static -> shfl broadcasts).
__global__ __launch_bounds__(64) void potf2_k(float* __restrict__ Mg, int e) {
  int l = threadIdx.x;
  float r[64];
  #pragma unroll
  for (int k = 0; k < 64; k++) r[k] = Mg[(size_t)(e + l) * 1024 + e + k];
  #pragma unroll
  for (int j = 0; j < 64; j++) {
    float dj = __shfl(r[j], j, 64);
    float Ljj = sqrtf(fmaxf(dj, 1e-12f));
    float inv = 1.0f / Ljj;
    if (l == j) r[j] = Ljj;
    else if (l > j) r[j] *= inv;
    #pragma unroll
    for (int k = j + 1; k < 64; k++) {
      float Lkj = __shfl(r[j], k, 64);
      r[k] -= r[j] * Lkj;
    }
  }
  #pragma unroll
  for (int k = 0; k < 64; k++) if (k <= l) Mg[(size_t)(e + l) * 1024 + e + k] = r[k];
}

// Panel: rows below diag block solve against L11^T (one row per thread, y in registers).
__global__ __launch_bounds__(256) void chol_trsm_k(float* __restrict__ Mg, int e) {
  __shared__ float L11[64][65];
  int t = threadIdx.x;
  for (int i = t; i < 4096; i += 256) L11[i >> 6][i & 63] = Mg[(size_t)(e + (i >> 6)) * 1024 + e + (i & 63)];
  __syncthreads();
  int row = e + 64 + blockIdx.x * 256 + t;
  if (row >= 1024) return;
  float y[64];
  #pragma unroll
  for (int k = 0; k < 64; k++) y[k] = Mg[(size_t)row * 1024 + e + k];
  #pragma unroll
  for (int kk = 0; kk < 64; kk++) {
    float v = y[kk];
    #pragma unroll
    for (int m = 0; m < kk; m++) v -= L11[kk][m] * y[m];
    y[kk] = v / L11[kk][kk];
  }
  #pragma unroll
  for (int k = 0; k < 64; k++) Mg[(size_t)row * 1024 + e + k] = y[k];
}

// One block-row step of X = L^{-1} * RHS (1024 RHS columns; thread per column; coalesced).
__global__ __launch_bounds__(256) void trsm_rhs_k(const float* __restrict__ Mg, float* __restrict__ S, int e) {
  __shared__ float L11[64][65];
  int t = threadIdx.x;
  for (int i = t; i < 4096; i += 256) L11[i >> 6][i & 63] = Mg[(size_t)(e + (i >> 6)) * 1024 + e + (i & 63)];
  __syncthreads();
  int col = blockIdx.x * 256 + t;
  float y[64];
  #pragma unroll
  for (int k = 0; k < 64; k++) y[k] = S[(size_t)(e + k) * 1024 + col];
  #pragma unroll
  for (int kk = 0; kk < 64; kk++) {
    float v = y[kk];
    #pragma unroll
    for (int m = 0; m < kk; m++) v -= L11[kk][m] * y[m];
    y[kk] = v / L11[kk][kk];
  }
  #pragma unroll
  for (int k = 0; k < 64; k++) S[(size_t)(e + k) * 1024 + col] = y[k];
}

// Single-RHS blocked forward solve L w = b (one block, 1024 threads).
__global__ __launch_bounds__(1024) void trsv_fwd_k(const float* __restrict__ Lg, const float* __restrict__ bin,
    float* __restrict__ wout) {
  __shared__ float zs[1024];
  __shared__ float wsb[64];
  int t = threadIdx.x;
  zs[t] = bin[t];
  __syncthreads();
  for (int s = 0; s < 16; s++) {
    int e = s * 64;
    if (t < 64) {
      float rr[64];
      #pragma unroll
      for (int k = 0; k < 64; k++) rr[k] = Lg[(size_t)(e + t) * 1024 + e + k];
      float acc = zs[e + t];
      #pragma unroll
      for (int k = 0; k < 64; k++) {
        float cand = acc / rr[k];
        float wk = __shfl(cand, k, 64);
        if (t == k) wsb[k] = wk;
        if (t > k) acc -= rr[k] * wk;
      }
    }
    __syncthreads();
    if (t < 64) zs[e + t] = wsb[t];
    __syncthreads();
    if (t >= e + 64) {
      float a = zs[t];
      #pragma unroll
      for (int k = 0; k < 64; k++) a -= Lg[(size_t)t * 1024 + e + k] * wsb[k];
      zs[t] = a;
    }
    __syncthreads();
  }
  wout[t] = zs[t];
}

// Single-RHS blocked backward solve L^T u = b.
__global__ __launch_bounds__(1024) void trsv_bwd_k(const float* __restrict__ Lg, const float* __restrict__ bin,
    float* __restrict__ wout) {
  __shared__ float zs[1024];
  __shared__ float wsb[64];
  int t = threadIdx.x;
  zs[t] = bin[t];
  __syncthreads();
  for (int s = 15; s >= 0; s--) {
    int e = s * 64;
    if (t < 64) {
      float rr[64];
      #pragma unroll
      for (int k = 0; k < 64; k++) rr[k] = Lg[(size_t)(e + k) * 1024 + e + t];  // L^T row t of block
      float acc = zs[e + t];
      #pragma unroll
      for (int k = 63; k >= 0; k--) {
        float cand = acc / rr[k];
        float wk = __shfl(cand, k, 64);
        if (t == k) wsb[k] = wk;
        if (t < k) acc -= rr[k] * wk;
      }
    }
    __syncthreads();
    if (t < 64) zs[e + t] = wsb[t];
    __syncthreads();
    if (t < e) {
      float a = zs[t];
      #pragma unroll
      for (int k = 0; k < 64; k++) a -= Lg[(size_t)(e + k) * 1024 + t] * wsb[k];
      zs[t] = a;
    }
    __syncthreads();
  }
  wout[t] = zs[t];
}

// ===================== fused ODE unfolds (row-independent) =====================
__global__ __launch_bounds__(256) void ode_k(const float* __restrict__ w, const float* __restrict__ sig,
    const float* __restrict__ mu, const float* __restrict__ erev, const float* __restrict__ mask,
    const float* __restrict__ gleak, const float* __restrict__ vleak, const float* __restrict__ cm,
    const float* __restrict__ dvec, const float* __restrict__ ctrlv, const float* __restrict__ wns,
    const float* __restrict__ wds, const float* __restrict__ ow, const float* __restrict__ ob,
    const float* __restrict__ control, float* __restrict__ dout) {
  __shared__ float wm[1024], we[1024], sgs[1024], mus[1024];
  __shared__ float red[512];
  __shared__ float vsh;
  int i = blockIdx.x, t = threadIdx.x;
  for (int j = t; j < 1024; j += 256) {
    int idx = i * 1024 + j;
    float wmv = w[idx] * mask[idx];
    wm[j] = wmv;
    we[j] = wmv * erev[idx];
    sgs[j] = sig[idx];
    mus[j] = mu[idx];
  }
  float cmt = dvec[i] + cm[i] * 6.0f + ctrlv[i];
  float gl = gleak[i], vl = vleak[i];
  float numS = wns[i], denS = wds[i];
  float v = 0.0f;
  __syncthreads();
  for (int u = 0; u < 6; u++) {
    float n = 0.f, d = 0.f;
    for (int j = t; j < 1024; j += 256) {
      float sgm = 1.0f / (1.0f + expf(-sgs[j] * (v - mus[j])));
      n += we[j] * sgm;
      d += wm[j] * sgm;
    }
    red[t] = n; red[256 + t] = d;
    __syncthreads();
    for (int o = 128; o > 0; o >>= 1) {
      if (t < o) { red[t] += red[t + o]; red[256 + t] += red[256 + t + o]; }
      __syncthreads();
    }
    if (t == 0) {
      float num = red[0] + numS, den = red[256] + denS;
      vsh = (cmt * v + gl * vl + num) / (cmt + gl + den + 1e-8f);
    }
    __syncthreads();
    v = vsh;
    __syncthreads();
  }
  if (t == 0) {
    dout[i] = v * ow[i] + ob[i];
    dout[1024 + i] = v;
    dout[2048 + 1048576 + i] = ctrlv[i] + control[i];
  }
}

// ===================== host orchestration =====================

static void launch_chol(float* Mm, hipStream_t stream) {
  for (int s = 0; s < 16; s++) {
    int e = s * 64;
    potf2_k<<<1, 64, 0, stream>>>(Mm, e);
    int rb = 1024 - e - 64;
    if (rb > 0) {
      chol_trsm_k<<<(rb + 255) / 256, 256, 0, stream>>>(Mm, e);
      int e2 = e + 64;
      dim3 g((rb + 127) / 128, (rb + 127) / 128);
      gemm_k<0, 1, 1><<<g, 256, 0, stream>>>(Mm + (size_t)e2 * 1024 + e, Mm + (size_t)e2 * 1024 + e,
                                             Mm + (size_t)e2 * 1024 + e2, rb, rb, 64, 1024, 1024, 1024, 1);
    }
  }
}

static void launch_trisolve(const float* Mm, float* S, hipStream_t stream) {
  for (int s = 0; s < 16; s++) {
    int e = s * 64;
    trsm_rhs_k<<<4, 256, 0, stream>>>(Mm, S, e);
    int rb = 1024 - e - 64;
    if (rb > 0) {
      dim3 g(8, (rb + 127) / 128);
      gemm_k<0, 0, 1><<<g, 256, 0, stream>>>(Mm + (size_t)(e + 64) * 1024 + e, S + (size_t)e * 1024,
                                             S + (size_t)(e + 64) * 1024, rb, 1024, 64, 1024, 1024, 1024, 0);
    }
  }
}

extern "C" void kernel_launch(void* const* d_in, const int* in_sizes, int n_in,
                              void* d_out, int out_size, void* d_ws, size_t ws_size,
                              hipStream_t stream) {
  const float* inputs  = (const float*)d_in[0];
  const float* adj     = (const float*)d_in[1];
  const float* lap     = (const float*)d_in[2];
  const float* control = (const float*)d_in[3];
  const float* gleak   = (const float*)d_in[4];
  const float* vleak   = (const float*)d_in[5];
  const float* cm      = (const float*)d_in[6];
  const float* sigma   = (const float*)d_in[7];
  const float* mu      = (const float*)d_in[8];
  const float* w       = (const float*)d_in[9];
  const float* erev    = (const float*)d_in[10];
  const float* ssig    = (const float*)d_in[11];
  const float* smu     = (const float*)d_in[12];
  const float* sw      = (const float*)d_in[13];
  const float* serev   = (const float*)d_in[14];
  const float* mask    = (const float*)d_in[15];
  const float* smask   = (const float*)d_in[16];
  const float* iw      = (const float*)d_in[17];
  const float* ib      = (const float*)d_in[18];
  const float* ow      = (const float*)d_in[19];
  const float* ob      = (const float*)d_in[20];
  const float* aw      = (const float*)d_in[21];
  const float* ab      = (const float*)d_in[22];
  const float* gcw     = (const float*)d_in[23];
  const float* gcb     = (const float*)d_in[24];
  float* out = (float*)d_out;
  float* ws = (float*)d_ws;

  float* P0 = ws;
  float* P1 = ws + (size_t)MSZ;
  float* PA = ws + 2 * (size_t)MSZ;
  float* PB = ws + 3 * (size_t)MSZ;
  float* Mm = ws + 4 * (size_t)MSZ;
  float* S  = ws + 5 * (size_t)MSZ;
  float* vb = ws + 6 * (size_t)MSZ;
  float* xv = vb;            float* atte = vb + 1024;
  float* wns = vb + 2048;    float* wds  = vb + 3072;
  float* dA  = vb + 4096;    float* dB   = vb + 5120;
  float* yv  = vb + 6144;    float* tv   = vb + 7168;
  float* zv  = vb + 8192;    float* wv   = vb + 9216;
  float* uv  = vb + 10240;   float* gv   = vb + 11264;
  float* ctrlv = vb + 12288;

  // vector prep + P0 = diag(att_e)
  prep_k<<<1, 1024, 0, stream>>>(inputs, iw, ib, aw, ab, xv, atte);
  setdiag_k<<<4096, 256, 0, stream>>>(P0, atte);
  sens_k<<<1024, 256, 0, stream>>>(sw, ssig, smu, serev, smask, xv, wns, wds);
  // 4-layer GCN (matvec chain); final result in dB
  gcn_k<<<1024, 256, 0, stream>>>(adj, xv, dA, gcw, gcb);
  gcn_k<<<1024, 256, 0, stream>>>(adj, dA, dB, gcw, gcb);
  gcn_k<<<1024, 256, 0, stream>>>(adj, dB, dA, gcw, gcb);
  gcn_k<<<1024, 256, 0, stream>>>(adj, dA, dB, gcw, gcb);

  float* P = P0; float* Pn = P1;
  dim3 G8(8, 8);
  for (int it = 0; it < 6; it++) {
    // PA = P*A, PB = P*B, M = (PB)^T*B + R, S = (PB)^T*A, Pn = A^T*(PA)
    gemm_k<0, 0, 0><<<G8, 256, 0, stream>>>(P, adj, PA, 1024, 1024, 1024, 1024, 1024, 1024, 0);
    gemm_k<0, 0, 0><<<G8, 256, 0, stream>>>(P, lap, PB, 1024, 1024, 1024, 1024, 1024, 1024, 0);
    gemm_k<1, 0, 0><<<G8, 256, 0, stream>>>(PB, lap, Mm, 1024, 1024, 1024, 1024, 1024, 1024, 0);
    diagadd_k<<<4, 256, 0, stream>>>(Mm, atte);
    gemm_k<1, 0, 0><<<G8, 256, 0, stream>>>(PB, adj, S, 1024, 1024, 1024, 1024, 1024, 1024, 0);
    gemm_k<1, 0, 0><<<G8, 256, 0, stream>>>(adj, PA, Pn, 1024, 1024, 1024, 1024, 1024, 1024, 0);
    // M = L L^T ; X = L^{-1} S (in place); Pn -= X^T X ; Pn += Q
    launch_chol(Mm, stream);
    launch_trisolve(Mm, S, stream);
    gemm_k<1, 0, 1><<<G8, 256, 0, stream>>>(S, S, Pn, 1024, 1024, 1024, 1024, 1024, 1024, 0);
    diagadd_k<<<4, 256, 0, stream>>>(Pn, atte);
    float* tmp = P; P = Pn; Pn = tmp;
  }

  // Final K only needed as (K@x): solve M u = B^T P A x  (single RHS)
  gemm_k<0, 0, 0><<<G8, 256, 0, stream>>>(P, lap, PB, 1024, 1024, 1024, 1024, 1024, 1024, 0);
  gemm_k<1, 0, 0><<<G8, 256, 0, stream>>>(PB, lap, Mm, 1024, 1024, 1024, 1024, 1024, 1024, 0);
  diagadd_k<<<4, 256, 0, stream>>>(Mm, atte);
  launch_chol(Mm, stream);
  matvec_n_k<<<1024, 256, 0, stream>>>(adj, xv, yv);     // y = A x
  matvec_n_k<<<1024, 256, 0, stream>>>(P, yv, tv);       // t = P y
  matvec_t_k<<<4, 256, 0, stream>>>(lap, tv, zv);        // z = B^T t
  trsv_fwd_k<<<1, 1024, 0, stream>>>(Mm, zv, wv);
  trsv_bwd_k<<<1, 1024, 0, stream>>>(Mm, wv, uv);        // u = K@x
  gctrl_k<<<4, 256, 0, stream>>>(control, uv, gv);       // g = control - u/N
  matvec_t_k<<<4, 256, 0, stream>>>(lap, gv, ctrlv);     // ctrl = g @ B

  // ODE unfolds + outputs
  ode_k<<<1024, 256, 0, stream>>>(w, sigma, mu, erev, mask, gleak, vleak, cm, dB, ctrlv,
                                  wns, wds, ow, ob, control, out);
  copylap_k<<<1024, 256, 0, stream>>>((const float4*)lap, (float4*)(out + 2048));
}

// Round 2
// 15651.544 us; speedup vs baseline: 2.1794x; 2.1794x over previous
//
#include <hip/hip_runtime.h>

#define MSZ (1024*1024)
#define LD 1024

// ===================== small vector kernels =====================

__global__ __launch_bounds__(1024) void prep_k(const float* __restrict__ inp, const float* __restrict__ iw,
    const float* __restrict__ ib, const float* __restrict__ aw, const float* __restrict__ ab,
    float* __restrict__ xv, float* __restrict__ atte) {
  __shared__ float red[1024];
  int t = threadIdx.x;
  float x = inp[t] * iw[t] + ib[t];
  float s = x * (aw[t] + ab[0]);
  xv[t] = x;
  red[t] = s;
  __syncthreads();
  for (int o = 512; o > 0; o >>= 1) { if (t < o) red[t] = fmaxf(red[t], red[t + o]); __syncthreads(); }
  atte[t] = expf(s - red[0]);
}

__global__ void setdiag_k(float* __restrict__ P, const float* __restrict__ atte) {
  int idx = blockIdx.x * 256 + threadIdx.x;
  int r = idx >> 10, c = idx & 1023;
  P[idx] = (r == c) ? atte[r] : 0.0f;
}

__global__ __launch_bounds__(256) void sens_k(const float* __restrict__ sw, const float* __restrict__ ssig,
    const float* __restrict__ smu, const float* __restrict__ serev, const float* __restrict__ smask,
    const float* __restrict__ xv, float* __restrict__ wns, float* __restrict__ wds) {
  __shared__ float rn[256], rd[256];
  int i = blockIdx.x, t = threadIdx.x;
  float xi = xv[i];
  float n = 0.f, d = 0.f;
  for (int j = t; j < 1024; j += 256) {
    int idx = i * 1024 + j;
    float z = ssig[idx] * (xi - smu[idx]);
    float sg = 1.0f / (1.0f + expf(-z));
    float act = sw[idx] * sg * smask[idx];
    n += act * serev[idx];
    d += act;
  }
  rn[t] = n; rd[t] = d;
  __syncthreads();
  for (int o = 128; o > 0; o >>= 1) { if (t < o) { rn[t] += rn[t + o]; rd[t] += rd[t + o]; } __syncthreads(); }
  if (t == 0) { wns[i] = rn[0]; wds[i] = rd[0]; }
}

__global__ __launch_bounds__(256) void gcn_k(const float* __restrict__ adj, const float* __restrict__ hin,
    float* __restrict__ hout, const float* __restrict__ gcw, const float* __restrict__ gcb) {
  __shared__ float red[256];
  int i = blockIdx.x, t = threadIdx.x;
  float s = 0.f;
  for (int j = t; j < 1024; j += 256) s += adj[(size_t)i * 1024 + j] * hin[j];
  red[t] = s; __syncthreads();
  for (int o = 128; o > 0; o >>= 1) { if (t < o) red[t] += red[t + o]; __syncthreads(); }
  if (t == 0) hout[i] = fmaxf(gcw[0] * red[0] + gcb[0], 0.0f);
}

__global__ __launch_bounds__(256) void matvec_n_k(const float* __restrict__ M, const float* __restrict__ v,
    float* __restrict__ out) {
  __shared__ float red[256];
  int i = blockIdx.x, t = threadIdx.x;
  float s = 0.f;
  for (int j = t; j < 1024; j += 256) s += M[(size_t)i * 1024 + j] * v[j];
  red[t] = s; __syncthreads();
  for (int o = 128; o > 0; o >>= 1) { if (t < o) red[t] += red[t + o]; __syncthreads(); }
  if (t == 0) out[i] = red[0];
}

__global__ __launch_bounds__(256) void matvec_t_k(const float* __restrict__ M, const float* __restrict__ v,
    float* __restrict__ out) {
  int j = blockIdx.x * 256 + threadIdx.x;
  float s = 0.f;
  for (int i = 0; i < 1024; i++) s += M[(size_t)i * 1024 + j] * v[i];
  out[j] = s;
}

__global__ void gctrl_k(const float* __restrict__ control, const float* __restrict__ u, float* __restrict__ g) {
  int t = blockIdx.x * 256 + threadIdx.x;
  g[t] = control[t] - u[t] * (1.0f / 1024.0f);
}

__global__ void copylap_k(const float4* __restrict__ src, float4* __restrict__ dst) {
  int i = blockIdx.x * 256 + threadIdx.x;
  dst[i] = src[i];
}

// ===================== batched 64x128-tile fp32 GEMM (VALU) =====================
// Per z-plane descriptor: C [1024x1024] (mode 0: =, mode 1: -=)  op(A)*B
// TA=0: C = A*B ; TA=1: C = A^T*B. tri: skip tiles entirely above the diagonal.
// diag: add diag[i] at C[i][i].

struct GDesc { const float* A; const float* B; float* C; const float* diag; int tri; int mode; };
struct GArgs { GDesc d[3]; };

template<int TA>
__global__ __launch_bounds__(256) void gemm64x128_k(GArgs ga) {
  GDesc de = ga.d[blockIdx.z];
  int row0 = blockIdx.y * 64, col0 = blockIdx.x * 128;
  if (de.tri && row0 + 64 <= col0) return;
  __shared__ float As[32][64];
  __shared__ float Bs[32][128];
  const float* __restrict__ A = de.A;
  const float* __restrict__ B = de.B;
  int t = threadIdx.x;
  int tx = t & 15, ty = t >> 4;          // rows: tx*4 (broadcast-friendly), cols: ty*8
  float acc[4][8] = {};
  for (int k0 = 0; k0 < 1024; k0 += 32) {
    if (TA == 1) {
      #pragma unroll
      for (int h = 0; h < 2; h++) {
        int s = h * 256 + t;
        int bk = s >> 4, am = (s & 15) * 4;
        float4 v = *(const float4*)(A + (size_t)(k0 + bk) * LD + row0 + am);
        *(float4*)(&As[bk][am]) = v;
      }
    } else {
      #pragma unroll
      for (int h = 0; h < 2; h++) {
        int s = h * 256 + t;
        int am = s >> 3, k4 = (s & 7) * 4;
        float4 v = *(const float4*)(A + (size_t)(row0 + am) * LD + k0 + k4);
        As[k4 + 0][am] = v.x; As[k4 + 1][am] = v.y; As[k4 + 2][am] = v.z; As[k4 + 3][am] = v.w;
      }
    }
    #pragma unroll
    for (int h = 0; h < 4; h++) {
      int s = h * 256 + t;
      int bk = s >> 5, bn = (s & 31) * 4;
      float4 v = *(const float4*)(B + (size_t)(k0 + bk) * LD + col0 + bn);
      *(float4*)(&Bs[bk][bn]) = v;
    }
    __syncthreads();
    #pragma unroll
    for (int k = 0; k < 32; k++) {
      float4 a4 = *(float4*)(&As[k][tx * 4]);
      float4 b0 = *(float4*)(&Bs[k][ty * 8]);
      float4 b1 = *(float4*)(&Bs[k][ty * 8 + 4]);
      float a[4] = {a4.x, a4.y, a4.z, a4.w};
      float b[8] = {b0.x, b0.y, b0.z, b0.w, b1.x, b1.y, b1.z, b1.w};
      #pragma unroll
      for (int i = 0; i < 4; i++)
        #pragma unroll
        for (int j = 0; j < 8; j++)
          acc[i][j] += a[i] * b[j];
    }
    __syncthreads();
  }
  #pragma unroll
  for (int i = 0; i < 4; i++) {
    int gm = row0 + tx * 4 + i;
    if (de.diag) {
      int dc = gm - col0 - ty * 8;
      if (dc >= 0 && dc < 8) acc[i][dc] += de.diag[gm];
    }
    float* cp = de.C + (size_t)gm * LD + col0 + ty * 8;
    if (de.mode == 0) {
      float4 o0 = {acc[i][0], acc[i][1], acc[i][2], acc[i][3]};
      float4 o1 = {acc[i][4], acc[i][5], acc[i][6], acc[i][7]};
      *(float4*)cp = o0; *(float4*)(cp + 4) = o1;
    } else {
      float4 c0 = *(float4*)cp, c1 = *(float4*)(cp + 4);
      c0.x -= acc[i][0]; c0.y -= acc[i][1]; c0.z -= acc[i][2]; c0.w -= acc[i][3];
      c1.x -= acc[i][4]; c1.y -= acc[i][5]; c1.z -= acc[i][6]; c1.w -= acc[i][7];
      *(float4*)cp = c0; *(float4*)(cp + 4) = c1;
    }
  }
}

// ===================== Cholesky (block 64) — fused panel+RHS, fused update =====================

// In-wave 64x64 Cholesky of diag block at (e,e) of Mg (reads raw, result in r[] lower).
__device__ __forceinline__ void potf2_wave(const float* Mg, int e, int l, float r[64]) {
  #pragma unroll
  for (int k = 0; k < 64; k++) r[k] = Mg[(size_t)(e + l) * LD + e + k];
  #pragma unroll
  for (int j = 0; j < 64; j++) {
    float dj = __shfl(r[j], j, 64);
    float Ljj = sqrtf(fmaxf(dj, 1e-12f));
    float inv = 1.0f / Ljj;
    if (l == j) r[j] = Ljj;
    else if (l > j) r[j] *= inv;
    #pragma unroll
    for (int k = j + 1; k < 64; k++) {
      float Lkj = __shfl(r[j], k, 64);
      r[k] -= r[j] * Lkj;
    }
  }
}

// One step: every block locally factors the diag block into LDS; block 0 writes L11 to Lb.
// Blocks [0,nPanel): panel rows (row * L11^-T) -> Lb.  Blocks [nPanel,..): RHS cols of S (L11^-1 * S) in place.
__global__ __launch_bounds__(256) void cpr_k(const float* __restrict__ Mm, float* __restrict__ Lb,
    float* __restrict__ S, int e, int nPanel) {
  __shared__ float L11s[64][65];
  int t = threadIdx.x;
  if (t < 64) {
    float r[64];
    potf2_wave(Mm, e, t, r);
    #pragma unroll
    for (int k = 0; k < 64; k++) if (k <= t) L11s[t][k] = r[k];
    if (blockIdx.x == 0) {
      #pragma unroll
      for (int k = 0; k < 64; k++) if (k <= t) Lb[(size_t)(e + t) * LD + e + k] = r[k];
    }
  }
  __syncthreads();
  if ((int)blockIdx.x < nPanel) {
    int row = e + 64 + blockIdx.x * 256 + t;
    if (row < 1024) {
      float y[64];
      #pragma unroll
      for (int k = 0; k < 64; k++) y[k] = Mm[(size_t)row * LD + e + k];
      #pragma unroll
      for (int kk = 0; kk < 64; kk++) {
        float v = y[kk];
        #pragma unroll
        for (int m = 0; m < kk; m++) v -= L11s[kk][m] * y[m];
        y[kk] = v / L11s[kk][kk];
      }
      #pragma unroll
      for (int k = 0; k < 64; k++) Lb[(size_t)row * LD + e + k] = y[k];
    }
  } else if (S) {
    int col = ((int)blockIdx.x - nPanel) * 256 + t;
    float y[64];
    #pragma unroll
    for (int k = 0; k < 64; k++) y[k] = S[(size_t)(e + k) * LD + col];
    #pragma unroll
    for (int kk = 0; kk < 64; kk++) {
      float v = y[kk];
      #pragma unroll
      for (int m = 0; m < kk; m++) v -= L11s[kk][m] * y[m];
      y[kk] = v / L11s[kk][kk];
    }
    #pragma unroll
    for (int k = 0; k < 64; k++) S[(size_t)(e + k) * LD + col] = y[k];
  }
}

// Fused trailing update: blocks [0,nSyrk): lower-tri 64x64 tiles of Mm -= Lpanel*Lpanel^T;
// blocks [nSyrk,..): 64x128 tiles of S[e+64:, :] -= Lpanel @ W.
__global__ __launch_bounds__(256) void chupd_k(const float* __restrict__ Lb, float* __restrict__ Mm,
    float* __restrict__ S, int e, int nSyrk) {
  __shared__ float As[32][64];
  __shared__ float Bs[32][128];
  int e2 = e + 64;
  int t = threadIdx.x;
  int tx = t & 15, ty = t >> 4;
  int bid = blockIdx.x;
  if (bid < nSyrk) {
    int ti = (int)((sqrtf(8.0f * bid + 1.0f) - 1.0f) * 0.5f);
    while ((ti + 1) * (ti + 2) / 2 <= bid) ti++;
    while (ti * (ti + 1) / 2 > bid) ti--;
    int tj = bid - ti * (ti + 1) / 2;
    int ra = e2 + ti * 64, rbb = e2 + tj * 64;
    float acc[4][4] = {};
    for (int k0 = 0; k0 < 64; k0 += 32) {
      #pragma unroll
      for (int h = 0; h < 2; h++) {
        int s = h * 256 + t;
        int r = s >> 3, k4 = (s & 7) * 4;
        float4 v = *(const float4*)(Lb + (size_t)(ra + r) * LD + e + k0 + k4);
        As[k4 + 0][r] = v.x; As[k4 + 1][r] = v.y; As[k4 + 2][r] = v.z; As[k4 + 3][r] = v.w;
        float4 u = *(const float4*)(Lb + (size_t)(rbb + r) * LD + e + k0 + k4);
        Bs[k4 + 0][r] = u.x; Bs[k4 + 1][r] = u.y; Bs[k4 + 2][r] = u.z; Bs[k4 + 3][r] = u.w;
      }
      __syncthreads();
      #pragma unroll
      for (int k = 0; k < 32; k++) {
        float4 a4 = *(float4*)(&As[k][tx * 4]);
        float4 b4 = *(float4*)(&Bs[k][ty * 4]);
        float a[4] = {a4.x, a4.y, a4.z, a4.w};
        float b[4] = {b4.x, b4.y, b4.z, b4.w};
        #pragma unroll
        for (int i = 0; i < 4; i++)
          #pragma unroll
          for (int j = 0; j < 4; j++)
            acc[i][j] += a[i] * b[j];
      }
      __syncthreads();
    }
    #pragma unroll
    for (int i = 0; i < 4; i++) {
      float* cp = Mm + (size_t)(ra + tx * 4 + i) * LD + rbb + ty * 4;
      float4 c = *(float4*)cp;
      c.x -= acc[i][0]; c.y -= acc[i][1]; c.z -= acc[i][2]; c.w -= acc[i][3];
      *(float4*)cp = c;
    }
  } else {
    int q = bid - nSyrk;
    int ti = q >> 3, cb = q & 7;
    int ra = e2 + ti * 64, c0 = cb * 128;
    float acc[4][8] = {};
    for (int k0 = 0; k0 < 64; k0 += 32) {
      #pragma unroll
      for (int h = 0; h < 2; h++) {
        int s = h * 256 + t;
        int r = s >> 3, k4 = (s & 7) * 4;
        float4 v = *(const float4*)(Lb + (size_t)(ra + r) * LD + e + k0 + k4);
        As[k4 + 0][r] = v.x; As[k4 + 1][r] = v.y; As[k4 + 2][r] = v.z; As[k4 + 3][r] = v.w;
      }
      #pragma unroll
      for (int h = 0; h < 4; h++) {
        int s = h * 256 + t;
        int bk = s >> 5, c4 = (s & 31) * 4;
        float4 v = *(const float4*)(S + (size_t)(e + k0 + bk) * LD + c0 + c4);
        *(float4*)(&Bs[bk][c4]) = v;
      }
      __syncthreads();
      #pragma unroll
      for (int k = 0; k < 32; k++) {
        float4 a4 = *(float4*)(&As[k][tx * 4]);
        float4 b0 = *(float4*)(&Bs[k][ty * 8]);
        float4 b1 = *(float4*)(&Bs[k][ty * 8 + 4]);
        float a[4] = {a4.x, a4.y, a4.z, a4.w};
        float b[8] = {b0.x, b0.y, b0.z, b0.w, b1.x, b1.y, b1.z, b1.w};
        #pragma unroll
        for (int i = 0; i < 4; i++)
          #pragma unroll
          for (int j = 0; j < 8; j++)
            acc[i][j] += a[i] * b[j];
      }
      __syncthreads();
    }
    #pragma unroll
    for (int i = 0; i < 4; i++) {
      float* cp = S + (size_t)(ra + tx * 4 + i) * LD + c0 + ty * 8;
      float4 c0v = *(float4*)cp, c1v = *(float4*)(cp + 4);
      c0v.x -= acc[i][0]; c0v.y -= acc[i][1]; c0v.z -= acc[i][2]; c0v.w -= acc[i][3];
      c1v.x -= acc[i][4]; c1v.y -= acc[i][5]; c1v.z -= acc[i][6]; c1v.w -= acc[i][7];
      *(float4*)cp = c0v; *(float4*)(cp + 4) = c1v;
    }
  }
}

// Mirror lower triangle to upper + add diag(atte).
__global__ __launch_bounds__(256) void mirror_k(float* __restrict__ P, const float* __restrict__ atte) {
  __shared__ float tile[64][65];
  int b = blockIdx.x, t = threadIdx.x;
  int ti, tj;
  if (b < 16) { ti = b; tj = b; }
  else {
    int p = b - 16;
    ti = (int)((1.0f + sqrtf(1.0f + 8.0f * p)) * 0.5f);
    while (ti * (ti - 1) / 2 > p) ti--;
    while ((ti + 1) * ti / 2 <= p) ti++;
    tj = p - ti * (ti - 1) / 2;
  }
  #pragma unroll
  for (int h = 0; h < 4; h++) {
    int s = h * 256 + t;
    int r = s >> 4, c4 = (s & 15) * 4;
    *(float4*)(&tile[r][c4]) = *(const float4*)(P + (size_t)(ti * 64 + r) * LD + tj * 64 + c4);
  }
  __syncthreads();
  if (ti == tj) {
    #pragma unroll
    for (int h = 0; h < 4; h++) {
      int s = h * 256 + t;
      int r = s >> 4, c4 = (s & 15) * 4;
      #pragma unroll
      for (int j = 0; j < 4; j++) {
        int c = c4 + j;
        if (c > r) P[(size_t)(ti * 64 + r) * LD + tj * 64 + c] = tile[c][r];
        else if (c == r) P[(size_t)(ti * 64 + r) * LD + tj * 64 + c] = tile[r][r] + atte[ti * 64 + r];
      }
    }
  } else {
    #pragma unroll
    for (int h = 0; h < 4; h++) {
      int s = h * 256 + t;
      int r = s >> 4, c4 = (s & 15) * 4;
      float4 o = {tile[c4 + 0][r], tile[c4 + 1][r], tile[c4 + 2][r], tile[c4 + 3][r]};
      *(float4*)(P + (size_t)(tj * 64 + r) * LD + ti * 64 + c4) = o;
    }
  }
}

// ===================== single-RHS triangular solves =====================

__global__ __launch_bounds__(1024) void trsv_fwd_k(const float* __restrict__ Lg, const float* __restrict__ bin,
    float* __restrict__ wout) {
  __shared__ float zs[1024];
  __shared__ float wsb[64];
  int t = threadIdx.x;
  zs[t] = bin[t];
  __syncthreads();
  for (int s = 0; s < 16; s++) {
    int e = s * 64;
    if (t < 64) {
      float rr[64];
      #pragma unroll
      for (int k = 0; k < 64; k++) rr[k] = Lg[(size_t)(e + t) * LD + e + k];
      float acc = zs[e + t];
      #pragma unroll
      for (int k = 0; k < 64; k++) {
        float cand = acc / rr[k];
        float wk = __shfl(cand, k, 64);
        if (t == k) wsb[k] = wk;
        if (t > k) acc -= rr[k] * wk;
      }
    }
    __syncthreads();
    if (t < 64) zs[e + t] = wsb[t];
    __syncthreads();
    if (t >= e + 64) {
      float a = zs[t];
      #pragma unroll
      for (int k = 0; k < 64; k++) a -= Lg[(size_t)t * LD + e + k] * wsb[k];
      zs[t] = a;
    }
    __syncthreads();
  }
  wout[t] = zs[t];
}

__global__ __launch_bounds__(1024) void trsv_bwd_k(const float* __restrict__ Lg, const float* __restrict__ bin,
    float* __restrict__ wout) {
  __shared__ float zs[1024];
  __shared__ float wsb[64];
  int t = threadIdx.x;
  zs[t] = bin[t];
  __syncthreads();
  for (int s = 15; s >= 0; s--) {
    int e = s * 64;
    if (t < 64) {
      float rr[64];
      #pragma unroll
      for (int k = 0; k < 64; k++) rr[k] = Lg[(size_t)(e + k) * LD + e + t];
      float acc = zs[e + t];
      #pragma unroll
      for (int k = 63; k >= 0; k--) {
        float cand = acc / rr[k];
        float wk = __shfl(cand, k, 64);
        if (t == k) wsb[k] = wk;
        if (t < k) acc -= rr[k] * wk;
      }
    }
    __syncthreads();
    if (t < 64) zs[e + t] = wsb[t];
    __syncthreads();
    if (t < e) {
      float a = zs[t];
      #pragma unroll
      for (int k = 0; k < 64; k++) a -= Lg[(size_t)(e + k) * LD + t] * wsb[k];
      zs[t] = a;
    }
    __syncthreads();
  }
  wout[t] = zs[t];
}

// ===================== fused ODE unfolds =====================
__global__ __launch_bounds__(256) void ode_k(const float* __restrict__ w, const float* __restrict__ sig,
    const float* __restrict__ mu, const float* __restrict__ erev, const float* __restrict__ mask,
    const float* __restrict__ gleak, const float* __restrict__ vleak, const float* __restrict__ cm,
    const float* __restrict__ dvec, const float* __restrict__ ctrlv, const float* __restrict__ wns,
    const float* __restrict__ wds, const float* __restrict__ ow, const float* __restrict__ ob,
    const float* __restrict__ control, float* __restrict__ dout) {
  __shared__ float wm[1024], we[1024], sgs[1024], mus[1024];
  __shared__ float red[512];
  __shared__ float vsh;
  int i = blockIdx.x, t = threadIdx.x;
  for (int j = t; j < 1024; j += 256) {
    int idx = i * 1024 + j;
    float wmv = w[idx] * mask[idx];
    wm[j] = wmv;
    we[j] = wmv * erev[idx];
    sgs[j] = sig[idx];
    mus[j] = mu[idx];
  }
  float cmt = dvec[i] + cm[i] * 6.0f + ctrlv[i];
  float gl = gleak[i], vl = vleak[i];
  float numS = wns[i], denS = wds[i];
  float v = 0.0f;
  __syncthreads();
  for (int u = 0; u < 6; u++) {
    float n = 0.f, d = 0.f;
    for (int j = t; j < 1024; j += 256) {
      float sgm = 1.0f / (1.0f + expf(-sgs[j] * (v - mus[j])));
      n += we[j] * sgm;
      d += wm[j] * sgm;
    }
    red[t] = n; red[256 + t] = d;
    __syncthreads();
    for (int o = 128; o > 0; o >>= 1) {
      if (t < o) { red[t] += red[t + o]; red[256 + t] += red[256 + t + o]; }
      __syncthreads();
    }
    if (t == 0) {
      float num = red[0] + numS, den = red[256] + denS;
      vsh = (cmt * v + gl * vl + num) / (cmt + gl + den + 1e-8f);
    }
    __syncthreads();
    v = vsh;
    __syncthreads();
  }
  if (t == 0) {
    dout[i] = v * ow[i] + ob[i];
    dout[1024 + i] = v;
    dout[2048 + 1048576 + i] = ctrlv[i] + control[i];
  }
}

// ===================== host orchestration =====================

static void launch_chol_tri(const float* Mm, float* Lb, float* S, hipStream_t stream) {
  for (int s = 0; s < 16; s++) {
    int e = s * 64;
    int rb = 1024 - e - 64;
    int nPanel = (rb + 255) / 256;
    int nRhs = S ? 4 : 0;
    int nBlocks = nPanel + nRhs; if (nBlocks < 1) nBlocks = 1;
    cpr_k<<<nBlocks, 256, 0, stream>>>(Mm, Lb, S, e, nPanel);
    if (rb > 0) {
      int nt = rb / 64;
      int nSyrk = nt * (nt + 1) / 2;
      int nUpd = nSyrk + (S ? nt * 8 : 0);
      chupd_k<<<nUpd, 256, 0, stream>>>(Lb, (float*)Mm, S, e, nSyrk);
    }
  }
}

extern "C" void kernel_launch(void* const* d_in, const int* in_sizes, int n_in,
                              void* d_out, int out_size, void* d_ws, size_t ws_size,
                              hipStream_t stream) {
  const float* inputs  = (const float*)d_in[0];
  const float* adj     = (const float*)d_in[1];
  const float* lap     = (const float*)d_in[2];
  const float* control = (const float*)d_in[3];
  const float* gleak   = (const float*)d_in[4];
  const float* vleak   = (const float*)d_in[5];
  const float* cm      = (const float*)d_in[6];
  const float* sigma   = (const float*)d_in[7];
  const float* mu      = (const float*)d_in[8];
  const float* w       = (const float*)d_in[9];
  const float* erev    = (const float*)d_in[10];
  const float* ssig    = (const float*)d_in[11];
  const float* smu     = (const float*)d_in[12];
  const float* sw      = (const float*)d_in[13];
  const float* serev   = (const float*)d_in[14];
  const float* mask    = (const float*)d_in[15];
  const float* smask   = (const float*)d_in[16];
  const float* iw      = (const float*)d_in[17];
  const float* ib      = (const float*)d_in[18];
  const float* ow      = (const float*)d_in[19];
  const float* ob      = (const float*)d_in[20];
  const float* aw      = (const float*)d_in[21];
  const float* ab      = (const float*)d_in[22];
  const float* gcw     = (const float*)d_in[23];
  const float* gcb     = (const float*)d_in[24];
  float* out = (float*)d_out;
  float* ws = (float*)d_ws;

  float* P0 = ws;
  float* P1 = ws + (size_t)MSZ;
  float* PA = ws + 2 * (size_t)MSZ;   // doubles as Lbuf during Cholesky
  float* PB = ws + 3 * (size_t)MSZ;
  float* Mm = ws + 4 * (size_t)MSZ;
  float* S  = ws + 5 * (size_t)MSZ;
  float* vb = ws + 6 * (size_t)MSZ;
  float* xv = vb;            float* atte = vb + 1024;
  float* wns = vb + 2048;    float* wds  = vb + 3072;
  float* dA  = vb + 4096;    float* dB   = vb + 5120;
  float* yv  = vb + 6144;    float* tv   = vb + 7168;
  float* zv  = vb + 8192;    float* wv   = vb + 9216;
  float* uv  = vb + 10240;   float* gv   = vb + 11264;
  float* ctrlv = vb + 12288;

  prep_k<<<1, 1024, 0, stream>>>(inputs, iw, ib, aw, ab, xv, atte);
  setdiag_k<<<4096, 256, 0, stream>>>(P0, atte);
  sens_k<<<1024, 256, 0, stream>>>(sw, ssig, smu, serev, smask, xv, wns, wds);
  gcn_k<<<1024, 256, 0, stream>>>(adj, xv, dA, gcw, gcb);
  gcn_k<<<1024, 256, 0, stream>>>(adj, dA, dB, gcw, gcb);
  gcn_k<<<1024, 256, 0, stream>>>(adj, dB, dA, gcw, gcb);
  gcn_k<<<1024, 256, 0, stream>>>(adj, dA, dB, gcw, gcb);

  float* P = P0; float* Pn = P1;
  for (int it = 0; it < 6; it++) {
    GArgs g1 = {{ {P, adj, PA, nullptr, 0, 0}, {P, lap, PB, nullptr, 0, 0}, {nullptr,nullptr,nullptr,nullptr,0,0} }};
    gemm64x128_k<0><<<dim3(8, 16, 2), 256, 0, stream>>>(g1);
    GArgs g2 = {{ {PB, adj, S, nullptr, 0, 0}, {PB, lap, Mm, atte, 1, 0}, {adj, PA, Pn, nullptr, 1, 0} }};
    gemm64x128_k<1><<<dim3(8, 16, 3), 256, 0, stream>>>(g2);
    launch_chol_tri(Mm, PA, S, stream);        // L in PA; S <- X = L^-1 S
    GArgs g3 = {{ {S, S, Pn, nullptr, 1, 1}, {nullptr,nullptr,nullptr,nullptr,0,0}, {nullptr,nullptr,nullptr,nullptr,0,0} }};
    gemm64x128_k<1><<<dim3(8, 16, 1), 256, 0, stream>>>(g3);  // Pn -= X^T X (lower)
    mirror_k<<<136, 256, 0, stream>>>(Pn, atte);              // mirror + add Q
    float* tmp = P; P = Pn; Pn = tmp;
  }

  // Final: u = K x via M u = B^T P A x
  GArgs g4 = {{ {P, lap, PB, nullptr, 0, 0}, {nullptr,nullptr,nullptr,nullptr,0,0}, {nullptr,nullptr,nullptr,nullptr,0,0} }};
  gemm64x128_k<0><<<dim3(8, 16, 1), 256, 0, stream>>>(g4);
  GArgs g5 = {{ {PB, lap, Mm, atte, 1, 0}, {nullptr,nullptr,nullptr,nullptr,0,0}, {nullptr,nullptr,nullptr,nullptr,0,0} }};
  gemm64x128_k<1><<<dim3(8, 16, 1), 256, 0, stream>>>(g5);
  launch_chol_tri(Mm, PA, nullptr, stream);    // L in PA
  matvec_n_k<<<1024, 256, 0, stream>>>(adj, xv, yv);
  matvec_n_k<<<1024, 256, 0, stream>>>(P, yv, tv);
  matvec_t_k<<<4, 256, 0, stream>>>(lap, tv, zv);
  trsv_fwd_k<<<1, 1024, 0, stream>>>(PA, zv, wv);
  trsv_bwd_k<<<1, 1024, 0, stream>>>(PA, wv, uv);
  gctrl_k<<<4, 256, 0, stream>>>(control, uv, gv);
  matvec_t_k<<<4, 256, 0, stream>>>(lap, gv, ctrlv);

  ode_k<<<1024, 256, 0, stream>>>(w, sigma, mu, erev, mask, gleak, vleak, cm, dB, ctrlv,
                                  wns, wds, ow, ob, control, out);
  copylap_k<<<1024, 256, 0, stream>>>((const float4*)lap, (float4*)(out + 2048));
}